// Round 6
// baseline (274.316 us; speedup 1.0000x reference)
//
#include <hip/hip_runtime.h>

// GCN3 round 6: gemm1+gemm2 fused (h1 bf16 stays in LDS, B-frags streamed
// from global frag-major layout), prep+bin fused (bcur via memset).
// CSR: bucketed counting sort, u16 indices. Aggregations gather bf16.

typedef __attribute__((ext_vector_type(8))) short short8;   // 8 bf16 (4 VGPR)
typedef __attribute__((ext_vector_type(4))) float f32x4;    // MFMA C/D

static __device__ __forceinline__ unsigned short f2bf(float f){
  union { float f; unsigned u; } v; v.f = f;
  unsigned r = v.u + 0x7FFF + ((v.u >> 16) & 1);            // RNE
  return (unsigned short)(r >> 16);
}
static __device__ __forceinline__ float2 bf2f2(unsigned u){
  union { unsigned u; float f; } a, b;
  a.u = u << 16; b.u = u & 0xffff0000u;
  return make_float2(a.f, b.f);
}

// ---------------- fused: edge binning + W frag-pack + x->bf16 ----------------
// blocks [0,binB): bin edges into buckets (bcur pre-zeroed via memset)
// blocks [binB,binB+256): weight frag-pack; rest: x fp32->bf16
__global__ __launch_bounds__(256) void k_prepbin(
    const int* __restrict__ src, const int* __restrict__ dst,
    int* __restrict__ bcur, unsigned* __restrict__ pairs, int E, int binB,
    const float* __restrict__ W1, const float* __restrict__ W2,
    unsigned short* __restrict__ Wf1, unsigned short* __restrict__ Wf2,
    const float4* __restrict__ x, uint2* __restrict__ xb, int nv){
  __shared__ int cl[256];
  int blk = blockIdx.x;
  int tid = threadIdx.x;
  if (blk < binB){
    int e0 = blk * 4096 + tid;
    cl[tid] = 0; __syncthreads();
    #pragma unroll
    for (int i = 0; i < 16; i++){
      int e = e0 + i*256;
      if (e < E) atomicAdd(&cl[dst[e] >> 8], 1);
    }
    __syncthreads();
    int c = cl[tid];
    int g = (c > 0) ? atomicAdd(&bcur[tid], c) : 0;   // reserve contiguous run
    cl[tid] = g;
    __syncthreads();
    #pragma unroll
    for (int i = 0; i < 16; i++){
      int e = e0 + i*256;
      if (e < E){
        int d = dst[e];
        int b = d >> 8;
        int p = atomicAdd(&cl[b], 1);
        pairs[(b << 13) + p] = (unsigned)src[e] | ((unsigned)(d & 255) << 16);
      }
    }
  } else if (blk < binB + 256){
    int t = (blk - binB)*256 + tid;                   // 65536 pack threads
    if (t < 32768){
      int j = t & 7, lane = (t>>3) & 63, kt = (t>>9) & 3, nt = t >> 11;
      int nn = nt*16 + (lane & 15);
      int kk = kt*32 + (lane>>4)*8 + j;
      Wf1[t] = f2bf(W1[kk*256 + nn]);
    } else {
      int o = t - 32768;
      int j = o & 7, lane = (o>>3) & 63, nt = (o>>9) & 7, kt = o >> 12;
      int nn = nt*16 + (lane & 15);
      int kk = kt*32 + (lane>>4)*8 + j;
      Wf2[o] = f2bf(W2[kk*128 + nn]);
    }
  } else {
    int i = (blk - binB - 256)*256 + tid;
    if (i < nv){
      float4 v = x[i];
      xb[i] = make_uint2((unsigned)f2bf(v.x) | ((unsigned)f2bf(v.y) << 16),
                         (unsigned)f2bf(v.z) | ((unsigned)f2bf(v.w) << 16));
    }
  }
}

// one block per bucket: node histogram + scans -> rowptr/cnt/dis + csr scatter
__global__ __launch_bounds__(256) void k_place(
    const int* __restrict__ bcur, const unsigned* __restrict__ pairs,
    unsigned short* __restrict__ csr_src, int* __restrict__ rowptr,
    int* __restrict__ cnt, float* __restrict__ dis, int n, int nb){
  __shared__ int sh[256];
  __shared__ int ncnt[256];
  int t = threadIdx.x;
  int b = blockIdx.x;
  int v = (t < nb) ? bcur[t] : 0;
  sh[t] = v; __syncthreads();
  for (int off = 1; off < 256; off <<= 1){
    int x = (t >= off) ? sh[t-off] : 0;
    __syncthreads(); sh[t] += x; __syncthreads();
  }
  int csr_base = (b == 0) ? 0 : sh[b-1];
  int cnt_b = bcur[b];
  ncnt[t] = 0; __syncthreads();
  const unsigned* P = pairs + ((size_t)b << 13);
  for (int i = t; i < cnt_b; i += 256) atomicAdd(&ncnt[P[i] >> 16], 1);
  __syncthreads();
  int c = ncnt[t];
  sh[t] = c; __syncthreads();
  for (int off = 1; off < 256; off <<= 1){
    int x = (t >= off) ? sh[t-off] : 0;
    __syncthreads(); sh[t] += x; __syncthreads();
  }
  int noff = sh[t] - c;
  int node = (b << 8) + t;
  if (node < n){
    rowptr[node] = csr_base + noff;
    cnt[node] = c;
    dis[node] = rsqrtf((float)(c + 1));           // +1 self loop
  }
  ncnt[t] = noff; __syncthreads();
  for (int i = t; i < cnt_b; i += 256){
    unsigned u = P[i];
    int p = atomicAdd(&ncnt[u >> 16], 1);
    csr_src[csr_base + p] = (unsigned short)(u & 0xffff);
  }
}

// ---------------- aggregation L1: bf16 gather -> xa bf16 ----------------
__global__ void k_aggL1(const unsigned* __restrict__ xb, unsigned* __restrict__ out,
                        const int* __restrict__ rowptr, const int* __restrict__ cnt,
                        const unsigned short* __restrict__ csr_src,
                        const float* __restrict__ dis, int n){
  int t = threadIdx.x;
  int lane = t & 63;
  int node = blockIdx.x*4 + (t >> 6);
  if (node >= n) return;
  float di = dis[node];
  float2 v = bf2f2(xb[(size_t)node*64 + lane]);
  float2 acc = make_float2(di*v.x, di*v.y);
  int start = rowptr[node];
  int mm = cnt[node];
  int j = 0;
  for (; j + 15 < mm; j += 16){
    int s[16]; unsigned uv[16]; float w[16];
    #pragma unroll
    for (int q = 0; q < 16; q++) s[q] = csr_src[start+j+q];
    #pragma unroll
    for (int q = 0; q < 16; q++){ w[q] = dis[s[q]]; uv[q] = xb[(size_t)s[q]*64 + lane]; }
    #pragma unroll
    for (int q = 0; q < 16; q++){
      float2 u = bf2f2(uv[q]);
      acc.x = fmaf(w[q], u.x, acc.x); acc.y = fmaf(w[q], u.y, acc.y);
    }
  }
  for (; j + 3 < mm; j += 4){
    int s[4]; unsigned uv[4]; float w[4];
    #pragma unroll
    for (int q = 0; q < 4; q++) s[q] = csr_src[start+j+q];
    #pragma unroll
    for (int q = 0; q < 4; q++){ w[q] = dis[s[q]]; uv[q] = xb[(size_t)s[q]*64 + lane]; }
    #pragma unroll
    for (int q = 0; q < 4; q++){
      float2 u = bf2f2(uv[q]);
      acc.x = fmaf(w[q], u.x, acc.x); acc.y = fmaf(w[q], u.y, acc.y);
    }
  }
  for (; j < mm; j++){
    int s = csr_src[start+j];
    float2 u = bf2f2(xb[(size_t)s*64 + lane]);
    float w = dis[s];
    acc.x = fmaf(w, u.x, acc.x); acc.y = fmaf(w, u.y, acc.y);
  }
  acc.x *= di; acc.y *= di;
  out[(size_t)node*64 + lane] =
      (unsigned)f2bf(acc.x) | ((unsigned)f2bf(acc.y) << 16);
}

// ---------------- aggregation L2: bf16 gather -> h2 fp32 (+b2,relu) + u=h2.W3 ----------------
__global__ void k_aggL2(const unsigned* __restrict__ t2b, float* __restrict__ h2,
                        const int* __restrict__ rowptr, const int* __restrict__ cnt,
                        const unsigned short* __restrict__ csr_src,
                        const float* __restrict__ dis,
                        const float* __restrict__ b2, const float* __restrict__ W3,
                        float* __restrict__ u, int n){
  int t = threadIdx.x;
  int lane = t & 63;
  int node = blockIdx.x*4 + (t >> 6);
  if (node >= n) return;
  float di = dis[node];
  float2 v = bf2f2(t2b[(size_t)node*64 + lane]);
  float2 acc = make_float2(di*v.x, di*v.y);
  int start = rowptr[node];
  int mm = cnt[node];
  int j = 0;
  for (; j + 15 < mm; j += 16){
    int s[16]; unsigned uv[16]; float w[16];
    #pragma unroll
    for (int q = 0; q < 16; q++) s[q] = csr_src[start+j+q];
    #pragma unroll
    for (int q = 0; q < 16; q++){ w[q] = dis[s[q]]; uv[q] = t2b[(size_t)s[q]*64 + lane]; }
    #pragma unroll
    for (int q = 0; q < 16; q++){
      float2 uu = bf2f2(uv[q]);
      acc.x = fmaf(w[q], uu.x, acc.x); acc.y = fmaf(w[q], uu.y, acc.y);
    }
  }
  for (; j + 3 < mm; j += 4){
    int s[4]; unsigned uv[4]; float w[4];
    #pragma unroll
    for (int q = 0; q < 4; q++) s[q] = csr_src[start+j+q];
    #pragma unroll
    for (int q = 0; q < 4; q++){ w[q] = dis[s[q]]; uv[q] = t2b[(size_t)s[q]*64 + lane]; }
    #pragma unroll
    for (int q = 0; q < 4; q++){
      float2 uu = bf2f2(uv[q]);
      acc.x = fmaf(w[q], uu.x, acc.x); acc.y = fmaf(w[q], uu.y, acc.y);
    }
  }
  for (; j < mm; j++){
    int s = csr_src[start+j];
    float2 uu = bf2f2(t2b[(size_t)s*64 + lane]);
    float w = dis[s];
    acc.x = fmaf(w, uu.x, acc.x); acc.y = fmaf(w, uu.y, acc.y);
  }
  float2 b = ((const float2*)b2)[lane];
  acc.x = fmaxf(fmaf(di, acc.x, b.x), 0.0f);
  acc.y = fmaxf(fmaf(di, acc.y, b.y), 0.0f);
  ((float2*)h2)[(size_t)node*64 + lane] = acc;
  float up = fmaf(acc.x, W3[2*lane], acc.y * W3[2*lane+1]);
  #pragma unroll
  for (int off = 32; off > 0; off >>= 1) up += __shfl_down(up, off);
  if (lane == 0) u[node] = up;
}

// ---------------- fused GEMM1+GEMM2 ----------------
// 64 rows/block, 4 waves. Phase1: h1 = relu(xa@W1+b1) -> global fp32 + LDS bf16.
// Phase2: t2 = h1@W2 -> global bf16. B-frags streamed from global (L1-reused).
__global__ __launch_bounds__(256) void k_gemm12(
    const unsigned short* __restrict__ Xa,   // bf16 [n][128]
    const unsigned short* __restrict__ Wf1,  // [16nt][4kt][64][8] bf16
    const unsigned short* __restrict__ Wf2,  // [8kt][8nt][64][8] bf16
    const float* __restrict__ b1,
    float* __restrict__ h1,                  // fp32 [n][256]
    unsigned short* __restrict__ T2b,        // bf16 [n][128]
    int n)
{
  __shared__ unsigned short As1[64*136];     // 17 KB, xa tile (pad 136)
  __shared__ unsigned short As2[64*264];     // 33 KB, bf16 h1 tile (pad 264)
  int t = threadIdx.x;
  int row0 = blockIdx.x * 64;
  {
    const float4* src = (const float4*)Xa;   // 16 float4 per 128-col bf16 row
    #pragma unroll
    for (int i = 0; i < 4; i++){
      int f = i*256 + t, r = f >> 4, c = f & 15;
      float4 v = make_float4(0,0,0,0);
      if (row0 + r < n) v = src[(size_t)(row0+r)*16 + c];
      *(float4*)&As1[r*136 + c*8] = v;
    }
  }
  __syncthreads();
  int w = t >> 6, lane = t & 63, m = lane & 15, q = lane >> 4;
  int rbase = w*16;
  short8 af[4];
  #pragma unroll
  for (int kt = 0; kt < 4; kt++)
    af[kt] = *(const short8*)&As1[(rbase + m)*136 + kt*32 + q*8];
  f32x4 acc1[16];
  #pragma unroll
  for (int i = 0; i < 16; i++) acc1[i] = (f32x4){0.f,0.f,0.f,0.f};
  const short8* W1v = (const short8*)Wf1;
  #pragma unroll
  for (int nt = 0; nt < 16; nt++){
    #pragma unroll
    for (int kt = 0; kt < 4; kt++){
      short8 bfr = W1v[(nt*4 + kt)*64 + lane];
      acc1[nt] = __builtin_amdgcn_mfma_f32_16x16x32_bf16(af[kt], bfr, acc1[nt], 0, 0, 0);
    }
  }
  int rowa = row0 + rbase + q*4;
  #pragma unroll
  for (int nt = 0; nt < 16; nt++){
    float b = b1[nt*16 + m];
    #pragma unroll
    for (int r = 0; r < 4; r++){
      int rr = rowa + r;
      float o = fmaxf(acc1[nt][r] + b, 0.0f);
      if (rr < n) h1[(size_t)rr*256 + nt*16 + m] = o;
      As2[(rbase + q*4 + r)*264 + nt*16 + m] = f2bf(o);  // rows>=n: garbage, discarded
    }
  }
  __syncthreads();
  short8 af2[8];
  #pragma unroll
  for (int kt = 0; kt < 8; kt++)
    af2[kt] = *(const short8*)&As2[(rbase + m)*264 + kt*32 + q*8];
  f32x4 acc2[8];
  #pragma unroll
  for (int i = 0; i < 8; i++) acc2[i] = (f32x4){0.f,0.f,0.f,0.f};
  const short8* W2v = (const short8*)Wf2;
  #pragma unroll
  for (int nt = 0; nt < 8; nt++){
    #pragma unroll
    for (int kt = 0; kt < 8; kt++){
      short8 bfr = W2v[(kt*8 + nt)*64 + lane];
      acc2[nt] = __builtin_amdgcn_mfma_f32_16x16x32_bf16(af2[kt], bfr, acc2[nt], 0, 0, 0);
    }
  }
  #pragma unroll
  for (int nt = 0; nt < 8; nt++){
    #pragma unroll
    for (int r = 0; r < 4; r++){
      int rr = rowa + r;
      if (rr < n) T2b[(size_t)rr*128 + nt*16 + m] = f2bf(acc2[nt][r]);
    }
  }
}

// ---------------- final scalar aggregation ----------------
__global__ void k_agg1d(const float* __restrict__ u, float* __restrict__ y,
                        const int* __restrict__ rowptr, const int* __restrict__ cnt,
                        const unsigned short* __restrict__ csr_src,
                        const float* __restrict__ dis,
                        const float* __restrict__ b3, int n){
  int i = blockIdx.x*256 + threadIdx.x;
  if (i >= n) return;
  float di = dis[i];
  float acc = di * u[i];
  int s0 = rowptr[i], m = cnt[i];
  for (int j = 0; j < m; j++){
    int s = csr_src[s0+j];
    acc = fmaf(dis[s], u[s], acc);
  }
  y[i] = fmaf(di, acc, b3[0]);
}

extern "C" void kernel_launch(void* const* d_in, const int* in_sizes, int n_in,
                              void* d_out, int out_size, void* d_ws, size_t ws_size,
                              hipStream_t stream){
  const float* x  = (const float*)d_in[0];
  const int*  ei  = (const int*)d_in[1];
  const float* W1 = (const float*)d_in[2];
  const float* b1 = (const float*)d_in[3];
  const float* W2 = (const float*)d_in[4];
  const float* b2 = (const float*)d_in[5];
  const float* W3 = (const float*)d_in[6];
  const float* b3 = (const float*)d_in[7];
  const int N = in_sizes[0] / 128;
  const int E = in_sizes[1] / 2;
  const int* src = ei;
  const int* dst = ei + E;
  const int NB = (N + 255) >> 8;      // 196 buckets

  char* p = (char*)d_ws;
  auto alloc = [&](size_t bytes)->char*{
    char* r = p; p += (bytes + 255) & ~(size_t)255; return r;
  };
  int*   bcur    = (int*)  alloc(256*4);
  int*   rowptr  = (int*)  alloc((size_t)N*4);
  int*   cnt     = (int*)  alloc((size_t)N*4);
  float* dis     = (float*)alloc((size_t)N*4);
  unsigned* pairs = (unsigned*)alloc((size_t)NB*8192*4);
  unsigned short* csr_src = (unsigned short*)alloc((size_t)E*2);
  unsigned* xb   = (unsigned*)alloc((size_t)N*128*2);   // bf16 x
  unsigned* xa   = (unsigned*)alloc((size_t)N*128*2);   // bf16 agg(x)
  unsigned short* t2b = (unsigned short*)alloc((size_t)N*128*2); // bf16 h1@W2
  float* u       = (float*)alloc((size_t)N*4);
  unsigned short* wf1 = (unsigned short*)alloc(32768*2);
  unsigned short* wf2 = (unsigned short*)alloc(32768*2);

  float* y  = (float*)d_out;
  float* h1 = y + N;
  float* h2 = h1 + (size_t)N*256;

  int bb = (E + 4095)/4096;           // 196 bin blocks
  int nb = (N + 255)/256;
  int xv = N*32;                      // float4 count of x
  int xblk = (xv + 255)/256;

  hipMemsetAsync(bcur, 0, 256*4, stream);
  k_prepbin <<<bb + 256 + xblk, 256, 0, stream>>>(
      src, dst, bcur, pairs, E, bb, W1, W2, wf1, wf2,
      (const float4*)x, (uint2*)xb, xv);
  k_place   <<<NB, 256, 0, stream>>>(bcur, pairs, csr_src, rowptr, cnt, dis, N, NB);

  int ab = (N + 3)/4;
  int rb = (N + 63)/64;
  k_aggL1   <<<ab, 256, 0, stream>>>(xb, xa, rowptr, cnt, csr_src, dis, N);
  k_gemm12  <<<rb, 256, 0, stream>>>((const unsigned short*)xa, wf1, wf2, b1, h1, t2b, N);
  k_aggL2   <<<ab, 256, 0, stream>>>((const unsigned*)t2b, h2, rowptr, cnt, csr_src, dis, b2, W3, u, N);
  k_agg1d   <<<nb, 256, 0, stream>>>(u, y, rowptr, cnt, csr_src, dis, b3, N);
}

// Round 7
// 255.197 us; speedup vs baseline: 1.0749x; 1.0749x over previous
//
#include <hip/hip_runtime.h>

// GCN3 round 7: separate GEMMs again (r6 fusion was latency-bound, MfmaUtil
// 3.7%). New: A-fragments loaded DIRECT global->reg (A has no intra-block
// reuse; LDS round-trip was waste), weights LDS-staged (reused by 4 waves).
// gemm2 col-half split w/ repacked Wf2. Everything else as round 5/6.

typedef __attribute__((ext_vector_type(8))) short short8;   // 8 bf16 (4 VGPR)
typedef __attribute__((ext_vector_type(4))) float f32x4;    // MFMA C/D

static __device__ __forceinline__ unsigned short f2bf(float f){
  union { float f; unsigned u; } v; v.f = f;
  unsigned r = v.u + 0x7FFF + ((v.u >> 16) & 1);            // RNE
  return (unsigned short)(r >> 16);
}
static __device__ __forceinline__ float2 bf2f2(unsigned u){
  union { unsigned u; float f; } a, b;
  a.u = u << 16; b.u = u & 0xffff0000u;
  return make_float2(a.f, b.f);
}

// ---------------- fused: edge binning + W frag-pack + x->bf16 ----------------
__global__ __launch_bounds__(256) void k_prepbin(
    const int* __restrict__ src, const int* __restrict__ dst,
    int* __restrict__ bcur, unsigned* __restrict__ pairs, int E, int binB,
    const float* __restrict__ W1, const float* __restrict__ W2,
    unsigned short* __restrict__ Wf1, unsigned short* __restrict__ Wf2,
    const float4* __restrict__ x, uint2* __restrict__ xb, int nv){
  __shared__ int cl[256];
  int blk = blockIdx.x;
  int tid = threadIdx.x;
  if (blk < binB){
    int e0 = blk * 4096 + tid;
    cl[tid] = 0; __syncthreads();
    #pragma unroll
    for (int i = 0; i < 16; i++){
      int e = e0 + i*256;
      if (e < E) atomicAdd(&cl[dst[e] >> 8], 1);
    }
    __syncthreads();
    int c = cl[tid];
    int g = (c > 0) ? atomicAdd(&bcur[tid], c) : 0;   // reserve contiguous run
    cl[tid] = g;
    __syncthreads();
    #pragma unroll
    for (int i = 0; i < 16; i++){
      int e = e0 + i*256;
      if (e < E){
        int d = dst[e];
        int b = d >> 8;
        int p = atomicAdd(&cl[b], 1);
        pairs[(b << 13) + p] = (unsigned)src[e] | ((unsigned)(d & 255) << 16);
      }
    }
  } else if (blk < binB + 256){
    int t = (blk - binB)*256 + tid;                   // 65536 pack threads
    if (t < 32768){
      // Wf1 [16 nt][4 kt][64 lane][8 j] from W1[128][256]
      int j = t & 7, lane = (t>>3) & 63, kt = (t>>9) & 3, nt = t >> 11;
      int nn = nt*16 + (lane & 15);
      int kk = kt*32 + (lane>>4)*8 + j;
      Wf1[t] = f2bf(W1[kk*256 + nn]);
    } else {
      // Wf2 [2 h][8 kt][4 ntl][64 lane][8 j] from W2[256][128]; nt = h*4+ntl
      int o = t - 32768;
      int j = o & 7, lane = (o>>3) & 63, ntl = (o>>9) & 3, kt = (o>>11) & 7, h = o >> 14;
      int nn = (h*4 + ntl)*16 + (lane & 15);
      int kk = kt*32 + (lane>>4)*8 + j;
      Wf2[o] = f2bf(W2[kk*128 + nn]);
    }
  } else {
    int i = (blk - binB - 256)*256 + tid;
    if (i < nv){
      float4 v = x[i];
      xb[i] = make_uint2((unsigned)f2bf(v.x) | ((unsigned)f2bf(v.y) << 16),
                         (unsigned)f2bf(v.z) | ((unsigned)f2bf(v.w) << 16));
    }
  }
}

// one block per bucket: node histogram + scans -> rowptr/cnt/dis + csr scatter
__global__ __launch_bounds__(256) void k_place(
    const int* __restrict__ bcur, const unsigned* __restrict__ pairs,
    unsigned short* __restrict__ csr_src, int* __restrict__ rowptr,
    int* __restrict__ cnt, float* __restrict__ dis, int n, int nb){
  __shared__ int sh[256];
  __shared__ int ncnt[256];
  int t = threadIdx.x;
  int b = blockIdx.x;
  int v = (t < nb) ? bcur[t] : 0;
  sh[t] = v; __syncthreads();
  for (int off = 1; off < 256; off <<= 1){
    int x = (t >= off) ? sh[t-off] : 0;
    __syncthreads(); sh[t] += x; __syncthreads();
  }
  int csr_base = (b == 0) ? 0 : sh[b-1];
  int cnt_b = bcur[b];
  ncnt[t] = 0; __syncthreads();
  const unsigned* P = pairs + ((size_t)b << 13);
  for (int i = t; i < cnt_b; i += 256) atomicAdd(&ncnt[P[i] >> 16], 1);
  __syncthreads();
  int c = ncnt[t];
  sh[t] = c; __syncthreads();
  for (int off = 1; off < 256; off <<= 1){
    int x = (t >= off) ? sh[t-off] : 0;
    __syncthreads(); sh[t] += x; __syncthreads();
  }
  int noff = sh[t] - c;
  int node = (b << 8) + t;
  if (node < n){
    rowptr[node] = csr_base + noff;
    cnt[node] = c;
    dis[node] = rsqrtf((float)(c + 1));           // +1 self loop
  }
  ncnt[t] = noff; __syncthreads();
  for (int i = t; i < cnt_b; i += 256){
    unsigned u = P[i];
    int p = atomicAdd(&ncnt[u >> 16], 1);
    csr_src[csr_base + p] = (unsigned short)(u & 0xffff);
  }
}

// ---------------- aggregation L1: bf16 gather -> xa bf16 ----------------
__global__ void k_aggL1(const unsigned* __restrict__ xb, unsigned* __restrict__ out,
                        const int* __restrict__ rowptr, const int* __restrict__ cnt,
                        const unsigned short* __restrict__ csr_src,
                        const float* __restrict__ dis, int n){
  int t = threadIdx.x;
  int lane = t & 63;
  int node = blockIdx.x*4 + (t >> 6);
  if (node >= n) return;
  float di = dis[node];
  float2 v = bf2f2(xb[(size_t)node*64 + lane]);
  float2 acc = make_float2(di*v.x, di*v.y);
  int start = rowptr[node];
  int mm = cnt[node];
  int j = 0;
  for (; j + 15 < mm; j += 16){
    int s[16]; unsigned uv[16]; float w[16];
    #pragma unroll
    for (int q = 0; q < 16; q++) s[q] = csr_src[start+j+q];
    #pragma unroll
    for (int q = 0; q < 16; q++){ w[q] = dis[s[q]]; uv[q] = xb[(size_t)s[q]*64 + lane]; }
    #pragma unroll
    for (int q = 0; q < 16; q++){
      float2 u = bf2f2(uv[q]);
      acc.x = fmaf(w[q], u.x, acc.x); acc.y = fmaf(w[q], u.y, acc.y);
    }
  }
  for (; j + 3 < mm; j += 4){
    int s[4]; unsigned uv[4]; float w[4];
    #pragma unroll
    for (int q = 0; q < 4; q++) s[q] = csr_src[start+j+q];
    #pragma unroll
    for (int q = 0; q < 4; q++){ w[q] = dis[s[q]]; uv[q] = xb[(size_t)s[q]*64 + lane]; }
    #pragma unroll
    for (int q = 0; q < 4; q++){
      float2 u = bf2f2(uv[q]);
      acc.x = fmaf(w[q], u.x, acc.x); acc.y = fmaf(w[q], u.y, acc.y);
    }
  }
  for (; j < mm; j++){
    int s = csr_src[start+j];
    float2 u = bf2f2(xb[(size_t)s*64 + lane]);
    float w = dis[s];
    acc.x = fmaf(w, u.x, acc.x); acc.y = fmaf(w, u.y, acc.y);
  }
  acc.x *= di; acc.y *= di;
  out[(size_t)node*64 + lane] =
      (unsigned)f2bf(acc.x) | ((unsigned)f2bf(acc.y) << 16);
}

// ---------------- aggregation L2: bf16 gather -> h2 fp32 (+b2,relu) + u=h2.W3 ----------------
__global__ void k_aggL2(const unsigned* __restrict__ t2b, float* __restrict__ h2,
                        const int* __restrict__ rowptr, const int* __restrict__ cnt,
                        const unsigned short* __restrict__ csr_src,
                        const float* __restrict__ dis,
                        const float* __restrict__ b2, const float* __restrict__ W3,
                        float* __restrict__ u, int n){
  int t = threadIdx.x;
  int lane = t & 63;
  int node = blockIdx.x*4 + (t >> 6);
  if (node >= n) return;
  float di = dis[node];
  float2 v = bf2f2(t2b[(size_t)node*64 + lane]);
  float2 acc = make_float2(di*v.x, di*v.y);
  int start = rowptr[node];
  int mm = cnt[node];
  int j = 0;
  for (; j + 15 < mm; j += 16){
    int s[16]; unsigned uv[16]; float w[16];
    #pragma unroll
    for (int q = 0; q < 16; q++) s[q] = csr_src[start+j+q];
    #pragma unroll
    for (int q = 0; q < 16; q++){ w[q] = dis[s[q]]; uv[q] = t2b[(size_t)s[q]*64 + lane]; }
    #pragma unroll
    for (int q = 0; q < 16; q++){
      float2 uu = bf2f2(uv[q]);
      acc.x = fmaf(w[q], uu.x, acc.x); acc.y = fmaf(w[q], uu.y, acc.y);
    }
  }
  for (; j + 3 < mm; j += 4){
    int s[4]; unsigned uv[4]; float w[4];
    #pragma unroll
    for (int q = 0; q < 4; q++) s[q] = csr_src[start+j+q];
    #pragma unroll
    for (int q = 0; q < 4; q++){ w[q] = dis[s[q]]; uv[q] = t2b[(size_t)s[q]*64 + lane]; }
    #pragma unroll
    for (int q = 0; q < 4; q++){
      float2 uu = bf2f2(uv[q]);
      acc.x = fmaf(w[q], uu.x, acc.x); acc.y = fmaf(w[q], uu.y, acc.y);
    }
  }
  for (; j < mm; j++){
    int s = csr_src[start+j];
    float2 uu = bf2f2(t2b[(size_t)s*64 + lane]);
    float w = dis[s];
    acc.x = fmaf(w, uu.x, acc.x); acc.y = fmaf(w, uu.y, acc.y);
  }
  float2 b = ((const float2*)b2)[lane];
  acc.x = fmaxf(fmaf(di, acc.x, b.x), 0.0f);
  acc.y = fmaxf(fmaf(di, acc.y, b.y), 0.0f);
  ((float2*)h2)[(size_t)node*64 + lane] = acc;
  float up = fmaf(acc.x, W3[2*lane], acc.y * W3[2*lane+1]);
  #pragma unroll
  for (int off = 32; off > 0; off >>= 1) up += __shfl_down(up, off);
  if (lane == 0) u[node] = up;
}

// ---------------- GEMM1: xa bf16 @ W1 -> h1 fp32 (+b1,relu) + h1b bf16 ----------------
// 64 rows x 128-col half per block. A-frags direct global->reg (no reuse in
// block -> no LDS round-trip); W half staged in LDS (reused by 4 waves).
__global__ __launch_bounds__(256) void k_gemm1_mfma(
    const unsigned short* __restrict__ Xa, const unsigned short* __restrict__ Wf1,
    const float* __restrict__ bias, float* __restrict__ out,
    unsigned short* __restrict__ h1b, int n)
{
  __shared__ unsigned short Wl[8*4*64*8];   // 32 KB
  int t = threadIdx.x;
  int row0 = (blockIdx.x >> 1) * 64;
  int h = blockIdx.x & 1;
  int w = t >> 6, lane = t & 63, m = lane & 15, q = lane >> 4;
  int rbase = w*16;
  int rowm = row0 + rbase + m;
  int ra = (rowm < n) ? rowm : (n-1);       // clamp; bad rows discarded at store
  const short8* Arow = (const short8*)(Xa + (size_t)ra*128);
  short8 af[4];
  #pragma unroll
  for (int kt = 0; kt < 4; kt++) af[kt] = Arow[kt*4 + q];   // 16B @ kt*64B + q*16B
  {
    const float4* src = (const float4*)Wf1 + (size_t)h*2048;
    float4* dst = (float4*)Wl;
    #pragma unroll
    for (int i = 0; i < 8; i++) dst[i*256 + t] = src[i*256 + t];
  }
  __syncthreads();
  f32x4 acc[8];
  #pragma unroll
  for (int i = 0; i < 8; i++) acc[i] = (f32x4){0.f,0.f,0.f,0.f};
  const short8* Wv = (const short8*)Wl;
  #pragma unroll
  for (int nt = 0; nt < 8; nt++){
    #pragma unroll
    for (int kt = 0; kt < 4; kt++){
      short8 bfr = Wv[(nt*4 + kt)*64 + lane];
      acc[nt] = __builtin_amdgcn_mfma_f32_16x16x32_bf16(af[kt], bfr, acc[nt], 0, 0, 0);
    }
  }
  int rowa = row0 + rbase + q*4;
  int colb = h*128 + m;
  #pragma unroll
  for (int nt = 0; nt < 8; nt++){
    float b = bias[colb + nt*16];
    #pragma unroll
    for (int r = 0; r < 4; r++){
      int rr = rowa + r;
      if (rr < n){
        float o = fmaxf(acc[nt][r] + b, 0.0f);
        out[(size_t)rr*256 + colb + nt*16] = o;
        h1b[(size_t)rr*256 + colb + nt*16] = f2bf(o);
      }
    }
  }
}

// ---------------- GEMM2: h1b bf16 @ W2 -> t2 bf16; 64 rows x 64-col half ----------------
__global__ __launch_bounds__(256) void k_gemm2_mfma(
    const unsigned short* __restrict__ H1b, const unsigned short* __restrict__ Wf2,
    unsigned short* __restrict__ T2b, int n)
{
  __shared__ unsigned short Wl[32*64*8];    // 32 KB: 8 kt x 4 ntl frags
  int t = threadIdx.x;
  int row0 = (blockIdx.x >> 1) * 64;
  int h = blockIdx.x & 1;
  int w = t >> 6, lane = t & 63, m = lane & 15, q = lane >> 4;
  int rbase = w*16;
  int rowm = row0 + rbase + m;
  int ra = (rowm < n) ? rowm : (n-1);
  const short8* Arow = (const short8*)(H1b + (size_t)ra*256);
  short8 af[8];
  #pragma unroll
  for (int kt = 0; kt < 8; kt++) af[kt] = Arow[kt*4 + q];
  {
    const float4* src = (const float4*)Wf2 + (size_t)h*2048;
    float4* dst = (float4*)Wl;
    #pragma unroll
    for (int i = 0; i < 8; i++) dst[i*256 + t] = src[i*256 + t];
  }
  __syncthreads();
  f32x4 acc[4];
  #pragma unroll
  for (int i = 0; i < 4; i++) acc[i] = (f32x4){0.f,0.f,0.f,0.f};
  const short8* Wv = (const short8*)Wl;
  #pragma unroll
  for (int nt = 0; nt < 4; nt++){
    #pragma unroll
    for (int kt = 0; kt < 8; kt++){
      short8 bfr = Wv[(kt*4 + nt)*64 + lane];
      acc[nt] = __builtin_amdgcn_mfma_f32_16x16x32_bf16(af[kt], bfr, acc[nt], 0, 0, 0);
    }
  }
  int rowa = row0 + rbase + q*4;
  #pragma unroll
  for (int nt = 0; nt < 4; nt++){
    int col = h*64 + nt*16 + m;
    #pragma unroll
    for (int r = 0; r < 4; r++){
      int rr = rowa + r;
      if (rr < n) T2b[(size_t)rr*128 + col] = f2bf(acc[nt][r]);
    }
  }
}

// ---------------- final scalar aggregation ----------------
__global__ void k_agg1d(const float* __restrict__ u, float* __restrict__ y,
                        const int* __restrict__ rowptr, const int* __restrict__ cnt,
                        const unsigned short* __restrict__ csr_src,
                        const float* __restrict__ dis,
                        const float* __restrict__ b3, int n){
  int i = blockIdx.x*256 + threadIdx.x;
  if (i >= n) return;
  float di = dis[i];
  float acc = di * u[i];
  int s0 = rowptr[i], m = cnt[i];
  for (int j = 0; j < m; j++){
    int s = csr_src[s0+j];
    acc = fmaf(dis[s], u[s], acc);
  }
  y[i] = fmaf(di, acc, b3[0]);
}

extern "C" void kernel_launch(void* const* d_in, const int* in_sizes, int n_in,
                              void* d_out, int out_size, void* d_ws, size_t ws_size,
                              hipStream_t stream){
  const float* x  = (const float*)d_in[0];
  const int*  ei  = (const int*)d_in[1];
  const float* W1 = (const float*)d_in[2];
  const float* b1 = (const float*)d_in[3];
  const float* W2 = (const float*)d_in[4];
  const float* b2 = (const float*)d_in[5];
  const float* W3 = (const float*)d_in[6];
  const float* b3 = (const float*)d_in[7];
  const int N = in_sizes[0] / 128;
  const int E = in_sizes[1] / 2;
  const int* src = ei;
  const int* dst = ei + E;
  const int NB = (N + 255) >> 8;      // 196 buckets

  char* p = (char*)d_ws;
  auto alloc = [&](size_t bytes)->char*{
    char* r = p; p += (bytes + 255) & ~(size_t)255; return r;
  };
  int*   bcur    = (int*)  alloc(256*4);
  int*   rowptr  = (int*)  alloc((size_t)N*4);
  int*   cnt     = (int*)  alloc((size_t)N*4);
  float* dis     = (float*)alloc((size_t)N*4);
  unsigned* pairs = (unsigned*)alloc((size_t)NB*8192*4);
  unsigned short* csr_src = (unsigned short*)alloc((size_t)E*2);
  unsigned* xb   = (unsigned*)alloc((size_t)N*128*2);   // bf16 x
  unsigned* xa   = (unsigned*)alloc((size_t)N*128*2);   // bf16 agg(x)
  unsigned short* h1b = (unsigned short*)alloc((size_t)N*256*2); // bf16 h1
  unsigned short* t2b = (unsigned short*)alloc((size_t)N*128*2); // bf16 h1@W2
  float* u       = (float*)alloc((size_t)N*4);
  unsigned short* wf1 = (unsigned short*)alloc(32768*2);
  unsigned short* wf2 = (unsigned short*)alloc(32768*2);

  float* y  = (float*)d_out;
  float* h1 = y + N;
  float* h2 = h1 + (size_t)N*256;

  int bb = (E + 4095)/4096;           // 196 bin blocks
  int nb = (N + 255)/256;
  int xv = N*32;                      // float4 count of x
  int xblk = (xv + 255)/256;

  hipMemsetAsync(bcur, 0, 256*4, stream);
  k_prepbin <<<bb + 256 + xblk, 256, 0, stream>>>(
      src, dst, bcur, pairs, E, bb, W1, W2, wf1, wf2,
      (const float4*)x, (uint2*)xb, xv);
  k_place   <<<NB, 256, 0, stream>>>(bcur, pairs, csr_src, rowptr, cnt, dis, N, NB);

  int ab = (N + 3)/4;
  int rb = (N + 63)/64;
  k_aggL1     <<<ab,   256, 0, stream>>>(xb, xa, rowptr, cnt, csr_src, dis, N);
  k_gemm1_mfma<<<rb*2, 256, 0, stream>>>((const unsigned short*)xa, wf1, b1, h1, h1b, N);
  k_gemm2_mfma<<<rb*2, 256, 0, stream>>>(h1b, wf2, t2b, N);
  k_aggL2     <<<ab,   256, 0, stream>>>((const unsigned*)t2b, h2, rowptr, cnt, csr_src, dis, b2, W3, u, N);
  k_agg1d     <<<nb,   256, 0, stream>>>(u, y, rowptr, cnt, csr_src, dis, b3, N);
}